// Round 3
// baseline (382.043 us; speedup 1.0000x reference)
//
#include <hip/hip_runtime.h>
#include <stdint.h>

#define Bb 48
#define Ww 8192
#define Ff 64
#define Dd 128
#define TWt 64
#define NSLAB 32

// ws layout (bytes)
#define WS_GRAMP 0u                                   // 32*48*4096*4 = 25165824
#define WS_GRAM  25165824u                            // 48*4096*4    = 786432
#define WS_TWT   25952256u                            // 128*192*2    = 49152
#define WS_CWT   26001408u                            // 64*192*2     = 24576
#define WS_GBF   26025984u                            // 48*4096*2    = 393216
#define WS_SWB   26419200u                            // 8192*64*2    = 1048576
#define WS_XBF   27467776u                            // 48*8192*64*2 = 50331648
#define WS_TOTAL (27467776ull + 50331648ull)          // 77799424

typedef __bf16 bf16x8 __attribute__((ext_vector_type(8)));
typedef float f32x4 __attribute__((ext_vector_type(4)));

__device__ __forceinline__ float bf2f(unsigned short u){
  union { unsigned int i; float f; } v; v.i = ((unsigned int)u) << 16; return v.f;
}
__device__ __forceinline__ unsigned short f2bf(float f){
  union { float f; unsigned int i; } v; v.f = f;
  unsigned int i = v.i;
  return (unsigned short)((i + 0x7fffu + ((i >> 16) & 1u)) >> 16);
}
__device__ __forceinline__ f32x4 mfma16(bf16x8 a, bf16x8 b, f32x4 c){
  return __builtin_amdgcn_mfma_f32_16x16x32_bf16(a, b, c, 0, 0, 0);
}

// ---------------------------------------------------------------------------
// merged weight prep: blocks 0..143 pack cwT/twT, blocks 144..399 convert seW_w
// ---------------------------------------------------------------------------
__global__ __launch_bounds__(256) void prep_weights(const float* __restrict__ ctx_w,
                                                    const float* __restrict__ token_w,
                                                    const float* __restrict__ seW_w,
                                                    unsigned short* __restrict__ cwT,
                                                    unsigned short* __restrict__ twT,
                                                    unsigned short* __restrict__ sWb,
                                                    int fast)
{
  const int bx = blockIdx.x;
  if (bx < 144){
    int idx = bx * 256 + threadIdx.x;
    const int ntw = Dd * 192;
    if (idx < ntw){
      int d = idx / 192, kim = idx % 192;
      int ktap = kim >> 6, fi = kim & 63;
      twT[idx] = f2bf(token_w[(d * Ff + fi) * 3 + ktap]);
    } else if (idx < ntw + Ff * 192){
      int i2 = idx - ntw;
      int f = i2 / 192, kim = i2 % 192;
      int ktap = kim >> 6, fi = kim & 63;
      cwT[i2] = f2bf(ctx_w[(f * Ff + fi) * 3 + ktap]);
    }
  } else if (fast){
    int i = ((bx - 144) * 256 + threadIdx.x) * 8;   // 524288 elems, 256 blocks
    float4 a0 = *(const float4*)(seW_w + i);
    float4 a1 = *(const float4*)(seW_w + i + 4);
    union { uint4 q; unsigned short s[8]; } u;
    u.s[0]=f2bf(a0.x); u.s[1]=f2bf(a0.y); u.s[2]=f2bf(a0.z); u.s[3]=f2bf(a0.w);
    u.s[4]=f2bf(a1.x); u.s[5]=f2bf(a1.y); u.s[6]=f2bf(a1.z); u.s[7]=f2bf(a1.w);
    *(uint4*)(sWb + i) = u.q;
  }
}

// ---------------------------------------------------------------------------
// gramP[slab][b] = partial srcn^T srcn over a 256-row K-chunk, reading x fp32
// directly; emits xbf (bf16 copy of x) inline; next-subtile loads prefetched
// into registers before the barrier so HBM latency hides under MFMA.
// grid (NSLAB, 48).
// ---------------------------------------------------------------------------
__global__ __launch_bounds__(256) void gram_kernel(const float* __restrict__ x,
                                                   unsigned short* __restrict__ xbf,
                                                   float* __restrict__ gramP,
                                                   int writeXbf)
{
  const int b = blockIdx.y;
  const int w_base = blockIdx.x * (Ww / NSLAB);   // 256 rows per slab
  const int t = threadIdx.x;
  const int lane = t & 63;
  const int wave = t >> 6;
  const int lrow = lane & 15;
  const int lk = lane >> 4;

  __shared__ unsigned short st[64 * 72];

  f32x4 acc[4] = {};

  const int wl = t >> 2;           // row within 64-row sub-tile
  const int f0 = (t & 3) * 16;     // 16 features per thread

  float v[16];
  {
    const float* xr = x + ((size_t)b * Ww + (size_t)(w_base + wl)) * Ff + f0;
    *(float4*)(v)      = *(const float4*)(xr);
    *(float4*)(v + 4)  = *(const float4*)(xr + 4);
    *(float4*)(v + 8)  = *(const float4*)(xr + 8);
    *(float4*)(v + 12) = *(const float4*)(xr + 12);
  }

  for (int sc = 0; sc < 4; ++sc) {
    const size_t rowg = (size_t)b * Ww + (size_t)(w_base + sc * 64 + wl);

    float ss = 0.f;
#pragma unroll
    for (int i = 0; i < 16; ++i) ss += v[i] * v[i];
    ss += __shfl_xor(ss, 1);
    ss += __shfl_xor(ss, 2);
    float rinv = rsqrtf(ss);

    union { uint4 q[2]; unsigned short s[16]; } u;
#pragma unroll
    for (int i = 0; i < 16; ++i){
      u.s[i] = f2bf(v[i]);
      st[(f0 + i) * 72 + wl] = f2bf(v[i] * rinv);
    }
    if (writeXbf){
      unsigned short* dst = xbf + rowg * Ff + f0;
      *(uint4*)(dst)     = u.q[0];
      *(uint4*)(dst + 8) = u.q[1];
    }

    // prefetch next sub-tile before the barrier (hides under MFMA section)
    float vn[16];
    if (sc < 3){
      const float* xr = x + ((size_t)b * Ww + (size_t)(w_base + (sc+1) * 64 + wl)) * Ff + f0;
      *(float4*)(vn)      = *(const float4*)(xr);
      *(float4*)(vn + 4)  = *(const float4*)(xr + 4);
      *(float4*)(vn + 8)  = *(const float4*)(xr + 8);
      *(float4*)(vn + 12) = *(const float4*)(xr + 12);
    }

    __syncthreads();
#pragma unroll
    for (int kc = 0; kc < 2; ++kc){
      const int kw = kc * 32 + lk * 8;
      bf16x8 bfr = *(const bf16x8*)(st + (wave * 16 + lrow) * 72 + kw);
#pragma unroll
      for (int mt = 0; mt < 4; ++mt){
        bf16x8 af = *(const bf16x8*)(st + (mt * 16 + lrow) * 72 + kw);
        acc[mt] = mfma16(af, bfr, acc[mt]);
      }
    }
    __syncthreads();

    if (sc < 3){
#pragma unroll
      for (int i = 0; i < 16; ++i) v[i] = vn[i];
    }
  }

  float* gb = gramP + ((size_t)(blockIdx.x * Bb + b)) * 4096;
#pragma unroll
  for (int mt = 0; mt < 4; ++mt)
#pragma unroll
    for (int r = 0; r < 4; ++r){
      int f = mt * 16 + lk * 4 + r;   // D row
      int g = wave * 16 + lrow;       // D col
      gb[f * 64 + g] = acc[mt][r];
    }
}

// ---------------------------------------------------------------------------
// reduce the NSLAB partial grams -> gram (fp32) and gbf (bf16). grid (192).
// ---------------------------------------------------------------------------
__global__ __launch_bounds__(256) void gram_reduce(const float* __restrict__ gramP,
                                                   float* __restrict__ gram,
                                                   unsigned short* __restrict__ gbf,
                                                   int fast)
{
  int i = blockIdx.x * 256 + threadIdx.x;   // 49152 threads, one float4 each
  int b = i >> 10;                          // 1024 float4 per batch
  int q = i & 1023;
  float sx = 0.f, sy = 0.f, sz = 0.f, sw = 0.f;
#pragma unroll
  for (int sl = 0; sl < NSLAB; ++sl){
    const float4 v = *(const float4*)(gramP + (((size_t)(sl * Bb + b)) << 12) + q * 4);
    sx += v.x; sy += v.y; sz += v.z; sw += v.w;
  }
  float4 s = make_float4(sx, sy, sz, sw);
  *(float4*)(gram + (((size_t)b) << 12) + q * 4) = s;
  if (fast){
    union { unsigned long long u; unsigned short h[4]; } u;
    u.h[0] = f2bf(sx); u.h[1] = f2bf(sy); u.h[2] = f2bf(sz); u.h[3] = f2bf(sw);
    *(unsigned long long*)(gbf + (((size_t)b) << 12) + q * 4) = u.u;
  }
}

// ---------------------------------------------------------------------------
// fused contextConv + structure-embedding + tokenConv. grid (128,48).
// LDS: xs (84x72) + sws (80x72); hsh ALIASES xs (dead after phase A).
// 23616 B -> 6 blocks/CU.
// ---------------------------------------------------------------------------
#define XSP 72
#define SSP 72
#define HSP 72

__global__ __launch_bounds__(256, 6) void fused_kernel(
    const float* __restrict__ x,
    const unsigned short* __restrict__ xbf,
    const float* __restrict__ ctx_b,
    const float* __restrict__ seW_w,
    const unsigned short* __restrict__ sWb,
    const float* __restrict__ seW_b,
    const float* __restrict__ gram,
    const unsigned short* __restrict__ gbf,
    const unsigned short* __restrict__ cwT,
    const unsigned short* __restrict__ twT,
    float* __restrict__ out,
    int fast)
{
  const int b = blockIdx.y;
  const int w0 = blockIdx.x * TWt;
  const int t = threadIdx.x;
  const int lane = t & 63;
  const int wave = t >> 6;
  const int lrow = lane & 15;
  const int lk = lane >> 4;

  __shared__ __align__(16) unsigned char smem[(84 * XSP + 80 * SSP) * 2];
  unsigned short* xs  = (unsigned short*)smem;
  unsigned short* sws = xs + 84 * XSP;
  unsigned short* hsh = xs;            // alias: xs dead after phase A

  // ---- stage x columns w0-2 .. w0+81 as bf16 (zero-pad outside [0,W)),
  //      plus sWb rows (w0-1 .. w0+78, circular) in fast mode ----
  if (fast){
    for (int item = t; item < 84 * 8; item += 256){
      int i = item >> 3, seg = item & 7;
      int c = w0 - 2 + i;
      uint4 val = make_uint4(0u,0u,0u,0u);
      if (c >= 0 && c < Ww) val = *(const uint4*)(xbf + ((size_t)b*Ww + c)*Ff + seg*8);
      *(uint4*)(xs + i*XSP + seg*8) = val;
    }
    for (int item = t; item < 80 * 8; item += 256){
      int i = item >> 3, seg = item & 7;
      int hc = (w0 - 1 + i) & (Ww - 1);
      *(uint4*)(sws + i*SSP + seg*8) = *(const uint4*)(sWb + (size_t)hc*Ff + seg*8);
    }
  } else {
    for (int item = t; item < 84 * 8; item += 256){
      int i = item >> 3, seg = item & 7;
      int c = w0 - 2 + i;
      union { uint4 q; unsigned short s[8]; } u;
      if (c >= 0 && c < Ww){
        const float* xr = x + ((size_t)b*Ww + c)*Ff + seg*8;
        float4 a0 = *(const float4*)(xr);
        float4 a1 = *(const float4*)(xr + 4);
        u.s[0]=f2bf(a0.x); u.s[1]=f2bf(a0.y); u.s[2]=f2bf(a0.z); u.s[3]=f2bf(a0.w);
        u.s[4]=f2bf(a1.x); u.s[5]=f2bf(a1.y); u.s[6]=f2bf(a1.z); u.s[7]=f2bf(a1.w);
      } else {
        u.q = make_uint4(0u,0u,0u,0u);
      }
      *(uint4*)(xs + i*XSP + seg*8) = u.q;
    }
  }
  __syncthreads();

  // ---- phase A: xc GEMM (M=80,K=192,N=64) + xse GEMM (M=80,K=64,N=64) ----
  const int nt = wave;
  bf16x8 cw_frag[6];
  {
    const unsigned short* p = cwT + (nt*16 + lrow)*192 + lk*8;
#pragma unroll
    for (int kc = 0; kc < 6; ++kc) cw_frag[kc] = *(const bf16x8*)(p + kc*32);
  }
  bf16x8 se_frag[2];
  if (fast){
    const unsigned short* gp = gbf + (size_t)b*4096 + (nt*16 + lrow)*64;  // gram symmetric
#pragma unroll
    for (int kc = 0; kc < 2; ++kc) se_frag[kc] = *(const bf16x8*)(gp + kc*32 + lk*8);
  } else {
    const float* gb = gram + (size_t)b * 4096;
#pragma unroll
    for (int kc = 0; kc < 2; ++kc){
      union { bf16x8 v; unsigned short s[8]; } u;
#pragma unroll
      for (int j = 0; j < 8; ++j){
        int g = kc*32 + lk*8 + j;
        u.s[j] = f2bf(gb[g*64 + nt*16 + lrow]);
      }
      se_frag[kc] = u.v;
    }
  }

  f32x4 xc_acc[5] = {};
  f32x4 se_acc[5] = {};

#pragma unroll
  for (int mt = 0; mt < 5; ++mt){
#pragma unroll
    for (int kc = 0; kc < 6; ++kc){
      int kim = kc*32 + lk*8;
      int ktap = kim >> 6, fi = kim & 63;
      bf16x8 a = *(const bf16x8*)(xs + (mt*16 + lrow + ktap)*XSP + fi);
      xc_acc[mt] = mfma16(a, cw_frag[kc], xc_acc[mt]);
    }
    if (fast){
#pragma unroll
      for (int kc = 0; kc < 2; ++kc){
        bf16x8 a = *(const bf16x8*)(sws + (mt*16 + lrow)*SSP + kc*32 + lk*8);
        se_acc[mt] = mfma16(a, se_frag[kc], se_acc[mt]);
      }
    } else {
      int hc = (w0 - 1 + mt*16 + lrow) & (Ww - 1);
      const float* sp = seW_w + (size_t)hc * Ff;
#pragma unroll
      for (int kc = 0; kc < 2; ++kc){
        union { bf16x8 v; unsigned short s[8]; } u;
        float4 a0 = *(const float4*)(sp + kc*32 + lk*8);
        float4 a1 = *(const float4*)(sp + kc*32 + lk*8 + 4);
        u.s[0]=f2bf(a0.x); u.s[1]=f2bf(a0.y); u.s[2]=f2bf(a0.z); u.s[3]=f2bf(a0.w);
        u.s[4]=f2bf(a1.x); u.s[5]=f2bf(a1.y); u.s[6]=f2bf(a1.z); u.s[7]=f2bf(a1.w);
        se_acc[mt] = mfma16(u.v, se_frag[kc], se_acc[mt]);
      }
    }
  }

  // all waves done reading xs before hsh (== xs) is overwritten
  __syncthreads();

  // epilogue: h = xc + ctx_b + relu(xse + seW_b)
  {
    float cb = ctx_b[nt*16 + lrow];
#pragma unroll
    for (int mt = 0; mt < 5; ++mt){
#pragma unroll
      for (int r = 0; r < 4; ++r){
        int j = mt*16 + lk*4 + r;
        if (j < 66){
          int hc = (w0 - 1 + j) & (Ww - 1);
          float se = se_acc[mt][r] + seW_b[hc];
          se = se > 0.f ? se : 0.f;
          hsh[j*HSP + nt*16 + lrow] = f2bf(xc_acc[mt][r] + cb + se);
        }
      }
    }
  }
  __syncthreads();

  // ---- patch circular-wrap slots (only tiles 0 and 127) ----
  if (blockIdx.x == 0 || blockIdx.x == (Ww/TWt - 1)){
    const int j  = (blockIdx.x == 0) ? 0 : 65;
    const int hc = (blockIdx.x == 0) ? (Ww - 1) : 0;
    if (t < 64){
      const int f = t;
      float a = ctx_b[f];
      for (int ktap = 0; ktap < 3; ++ktap){
        int c = hc + ktap - 1;
        if (c >= 0 && c < Ww){
          const float* xr = x + ((size_t)b*Ww + c)*Ff;
          const unsigned short* wr = cwT + f*192 + ktap*64;
          for (int fi = 0; fi < 64; ++fi) a += xr[fi] * bf2f(wr[fi]);
        }
      }
      const float* gb = gram + (size_t)b * 4096;
      const float* sp = seW_w + (size_t)hc * Ff;
      float se = seW_b[hc];
      for (int g = 0; g < 64; ++g) se += sp[g] * gb[g*64 + f];
      se = se > 0.f ? se : 0.f;
      hsh[j*HSP + f] = f2bf(a + se);
    }
    __syncthreads();
  }

  // ---- phase C: tokenConv GEMM (M=64, K=192, N=128) ----
  bf16x8 tw_frag[2][6];
#pragma unroll
  for (int q = 0; q < 2; ++q){
    const unsigned short* p = twT + ((wave*2 + q)*16 + lrow)*192 + lk*8;
#pragma unroll
    for (int kc = 0; kc < 6; ++kc) tw_frag[q][kc] = *(const bf16x8*)(p + kc*32);
  }
  f32x4 oacc[4][2] = {};
#pragma unroll
  for (int mt = 0; mt < 4; ++mt){
#pragma unroll
    for (int kc = 0; kc < 6; ++kc){
      int kim = kc*32 + lk*8;
      int ktap = kim >> 6, fi = kim & 63;
      bf16x8 a = *(const bf16x8*)(hsh + (mt*16 + lrow + ktap)*HSP + fi);
#pragma unroll
      for (int q = 0; q < 2; ++q)
        oacc[mt][q] = mfma16(a, tw_frag[q][kc], oacc[mt][q]);
    }
  }

  // ---- epilogue: direct coalesced stores (64 B segments per 16 lanes) ----
#pragma unroll
  for (int mt = 0; mt < 4; ++mt){
#pragma unroll
    for (int q = 0; q < 2; ++q)
#pragma unroll
      for (int r = 0; r < 4; ++r){
        int row = w0 + mt*16 + lk*4 + r;
        int d   = (wave*2 + q)*16 + lrow;
        out[((size_t)b*Ww + row)*Dd + d] = oacc[mt][q][r];
      }
  }
}

// ---------------------------------------------------------------------------
extern "C" void kernel_launch(void* const* d_in, const int* in_sizes, int n_in,
                              void* d_out, int out_size, void* d_ws, size_t ws_size,
                              hipStream_t stream)
{
  const float* x       = (const float*)d_in[0];
  const float* ctx_w   = (const float*)d_in[1];
  const float* ctx_b   = (const float*)d_in[2];
  const float* token_w = (const float*)d_in[3];
  const float* seW_w   = (const float*)d_in[4];
  const float* seW_b   = (const float*)d_in[5];
  float* out = (float*)d_out;

  char* ws = (char*)d_ws;
  float*          gramP = (float*)(ws + WS_GRAMP);
  float*          gram  = (float*)(ws + WS_GRAM);
  unsigned short* twT   = (unsigned short*)(ws + WS_TWT);
  unsigned short* cwT   = (unsigned short*)(ws + WS_CWT);
  unsigned short* gbf   = (unsigned short*)(ws + WS_GBF);
  unsigned short* sWb   = (unsigned short*)(ws + WS_SWB);
  unsigned short* xbf   = (unsigned short*)(ws + WS_XBF);

  const int fast = (ws_size >= (size_t)WS_TOTAL) ? 1 : 0;

  prep_weights<<<dim3(400), dim3(256), 0, stream>>>(ctx_w, token_w, seW_w, cwT, twT, sWb, fast);
  gram_kernel<<<dim3(NSLAB, Bb), dim3(256), 0, stream>>>(x, xbf, gramP, fast);
  gram_reduce<<<dim3(192), dim3(256), 0, stream>>>(gramP, gram, gbf, fast);
  fused_kernel<<<dim3(Ww/TWt, Bb), dim3(256), 0, stream>>>(
      x, xbf, ctx_b, seW_w, sWb, seW_b, gram, gbf, cwT, twT, out, fast);
}

// Round 4
// 367.635 us; speedup vs baseline: 1.0392x; 1.0392x over previous
//
#include <hip/hip_runtime.h>
#include <stdint.h>

#define Bb 48
#define Ww 8192
#define Ff 64
#define Dd 128
#define TWt 64
#define NSLAB 32

// ws layout (bytes)
#define WS_GRAMP 0u                                   // 32*48*4096*4 = 25165824
#define WS_GRAM  25165824u                            // 48*4096*4    = 786432
#define WS_TWT   25952256u                            // 128*192*2    = 49152
#define WS_CWT   26001408u                            // 64*192*2     = 24576
#define WS_GBF   26025984u                            // 48*4096*2    = 393216
#define WS_SWB   26419200u                            // 8192*64*2    = 1048576
#define WS_RINV  27467776u                            // 48*8192*4    = 1572864
#define WS_XBF   29040640u                            // 48*8192*64*2 = 50331648
#define WS_TOTAL (29040640ull + 50331648ull)          // 79372288

typedef __bf16 bf16x8 __attribute__((ext_vector_type(8)));
typedef float f32x4 __attribute__((ext_vector_type(4)));

__device__ __forceinline__ float bf2f(unsigned short u){
  union { unsigned int i; float f; } v; v.i = ((unsigned int)u) << 16; return v.f;
}
__device__ __forceinline__ unsigned short f2bf(float f){
  union { float f; unsigned int i; } v; v.f = f;
  unsigned int i = v.i;
  return (unsigned short)((i + 0x7fffu + ((i >> 16) & 1u)) >> 16);
}
__device__ __forceinline__ f32x4 mfma16(bf16x8 a, bf16x8 b, f32x4 c){
  return __builtin_amdgcn_mfma_f32_16x16x32_bf16(a, b, c, 0, 0, 0);
}

// XOR block-swizzled LDS offset: 64-short rows, 8-short (16B) blocks,
// block index XORed with (row&7). Kills the 8-way bank conflict the old
// pitch-72 layout had on stride-row ds_read_b128 (bank stride 4 mod 32).
__device__ __forceinline__ int swz(int row, int col){
  return row * 64 + ((((col >> 3) ^ (row & 7))) << 3) + (col & 7);
}

// ---------------------------------------------------------------------------
// merged weight prep: blocks 0..143 pack cwT/twT, blocks 144..399 convert seW_w
// ---------------------------------------------------------------------------
__global__ __launch_bounds__(256) void prep_weights(const float* __restrict__ ctx_w,
                                                    const float* __restrict__ token_w,
                                                    const float* __restrict__ seW_w,
                                                    unsigned short* __restrict__ cwT,
                                                    unsigned short* __restrict__ twT,
                                                    unsigned short* __restrict__ sWb,
                                                    int fast)
{
  const int bx = blockIdx.x;
  if (bx < 144){
    int idx = bx * 256 + threadIdx.x;
    const int ntw = Dd * 192;
    if (idx < ntw){
      int d = idx / 192, kim = idx % 192;
      int ktap = kim >> 6, fi = kim & 63;
      twT[idx] = f2bf(token_w[(d * Ff + fi) * 3 + ktap]);
    } else if (idx < ntw + Ff * 192){
      int i2 = idx - ntw;
      int f = i2 / 192, kim = i2 % 192;
      int ktap = kim >> 6, fi = kim & 63;
      cwT[i2] = f2bf(ctx_w[(f * Ff + fi) * 3 + ktap]);
    }
  } else if (fast){
    int i = ((bx - 144) * 256 + threadIdx.x) * 8;   // 524288 elems, 256 blocks
    float4 a0 = *(const float4*)(seW_w + i);
    float4 a1 = *(const float4*)(seW_w + i + 4);
    union { uint4 q; unsigned short s[8]; } u;
    u.s[0]=f2bf(a0.x); u.s[1]=f2bf(a0.y); u.s[2]=f2bf(a0.z); u.s[3]=f2bf(a0.w);
    u.s[4]=f2bf(a1.x); u.s[5]=f2bf(a1.y); u.s[6]=f2bf(a1.z); u.s[7]=f2bf(a1.w);
    *(uint4*)(sWb + i) = u.q;
  }
}

// ---------------------------------------------------------------------------
// xprep: streaming pass over x. Emits xbf (bf16 copy) + per-row rsqrt(sumsq).
// 4 threads per 64-feature row. grid 6144.
// ---------------------------------------------------------------------------
__global__ __launch_bounds__(256) void xprep(const float* __restrict__ x,
                                             unsigned short* __restrict__ xbf,
                                             float* __restrict__ rinvb)
{
  int tid = blockIdx.x * 256 + threadIdx.x;
  int row = tid >> 2;                // 0 .. 393215
  int f0  = (tid & 3) * 16;
  const float* xr = x + (size_t)row * Ff + f0;
  float v[16];
  *(float4*)(v)      = *(const float4*)(xr);
  *(float4*)(v + 4)  = *(const float4*)(xr + 4);
  *(float4*)(v + 8)  = *(const float4*)(xr + 8);
  *(float4*)(v + 12) = *(const float4*)(xr + 12);
  float ss = 0.f;
#pragma unroll
  for (int i = 0; i < 16; ++i) ss += v[i] * v[i];
  ss += __shfl_xor(ss, 1);
  ss += __shfl_xor(ss, 2);
  float rinv = rsqrtf(ss);
  union { uint4 q[2]; unsigned short s[16]; } u;
#pragma unroll
  for (int i = 0; i < 16; ++i) u.s[i] = f2bf(v[i]);
  unsigned short* dst = xbf + (size_t)row * Ff + f0;
  *(uint4*)(dst)     = u.q[0];
  *(uint4*)(dst + 8) = u.q[1];
  if ((tid & 3) == 0) rinvb[row] = rinv;
}

// ---------------------------------------------------------------------------
// gramP[slab][b] = partial srcn^T srcn over a 256-row K-chunk. Pure GEMM:
// fast path reads bf16 xbf + rinv table. LDS tile uses swizzled layout.
// grid (NSLAB, 48).
// ---------------------------------------------------------------------------
__global__ __launch_bounds__(256) void gram_kernel(const float* __restrict__ x,
                                                   const unsigned short* __restrict__ xbf,
                                                   const float* __restrict__ rinvb,
                                                   float* __restrict__ gramP,
                                                   int fast)
{
  const int b = blockIdx.y;
  const int w_base = blockIdx.x * (Ww / NSLAB);   // 256 rows per slab
  const int t = threadIdx.x;
  const int lane = t & 63;
  const int wave = t >> 6;
  const int lrow = lane & 15;
  const int lk = lane >> 4;

  __shared__ unsigned short st[64 * 64];

  f32x4 acc[4] = {};

  const int wl = t >> 2;           // row within 64-row sub-tile
  const int f0 = (t & 3) * 16;     // 16 features per thread

  for (int sc = 0; sc < (Ww / NSLAB) / 64; ++sc) {   // 4 iterations
    const int w0 = w_base + sc * 64;
    const size_t rowg = (size_t)b * Ww + (size_t)(w0 + wl);
    if (fast){
      union { uint4 q; unsigned short s[8]; } a0, a1;
      a0.q = *(const uint4*)(xbf + rowg * Ff + f0);
      a1.q = *(const uint4*)(xbf + rowg * Ff + f0 + 8);
      float rinv = rinvb[rowg];
#pragma unroll
      for (int i = 0; i < 8; ++i) st[swz(f0 + i, wl)]     = f2bf(bf2f(a0.s[i]) * rinv);
#pragma unroll
      for (int i = 0; i < 8; ++i) st[swz(f0 + 8 + i, wl)] = f2bf(bf2f(a1.s[i]) * rinv);
    } else {
      const float* xr = x + rowg * Ff + f0;
      float v[16];
      *(float4*)(v)      = *(const float4*)(xr);
      *(float4*)(v + 4)  = *(const float4*)(xr + 4);
      *(float4*)(v + 8)  = *(const float4*)(xr + 8);
      *(float4*)(v + 12) = *(const float4*)(xr + 12);
      float ss = 0.f;
#pragma unroll
      for (int i = 0; i < 16; ++i) ss += v[i] * v[i];
      ss += __shfl_xor(ss, 1);
      ss += __shfl_xor(ss, 2);
      float rinv = rsqrtf(ss);
#pragma unroll
      for (int i = 0; i < 16; ++i) st[swz(f0 + i, wl)] = f2bf(v[i] * rinv);
    }
    __syncthreads();
#pragma unroll
    for (int kc = 0; kc < 2; ++kc){
      const int kw = kc * 32 + lk * 8;
      bf16x8 bfr = *(const bf16x8*)(st + swz(wave * 16 + lrow, kw));
#pragma unroll
      for (int mt = 0; mt < 4; ++mt){
        bf16x8 af = *(const bf16x8*)(st + swz(mt * 16 + lrow, kw));
        acc[mt] = mfma16(af, bfr, acc[mt]);
      }
    }
    __syncthreads();
  }

  float* gb = gramP + ((size_t)(blockIdx.x * Bb + b)) * 4096;
#pragma unroll
  for (int mt = 0; mt < 4; ++mt)
#pragma unroll
    for (int r = 0; r < 4; ++r){
      int f = mt * 16 + lk * 4 + r;   // D row
      int g = wave * 16 + lrow;       // D col
      gb[f * 64 + g] = acc[mt][r];
    }
}

// ---------------------------------------------------------------------------
// reduce the NSLAB partial grams -> gram (fp32) and gbf (bf16). grid (192).
// ---------------------------------------------------------------------------
__global__ __launch_bounds__(256) void gram_reduce(const float* __restrict__ gramP,
                                                   float* __restrict__ gram,
                                                   unsigned short* __restrict__ gbf,
                                                   int fast)
{
  int i = blockIdx.x * 256 + threadIdx.x;   // 49152 threads, one float4 each
  int b = i >> 10;                          // 1024 float4 per batch
  int q = i & 1023;
  float sx = 0.f, sy = 0.f, sz = 0.f, sw = 0.f;
#pragma unroll
  for (int sl = 0; sl < NSLAB; ++sl){
    const float4 v = *(const float4*)(gramP + (((size_t)(sl * Bb + b)) << 12) + q * 4);
    sx += v.x; sy += v.y; sz += v.z; sw += v.w;
  }
  float4 s = make_float4(sx, sy, sz, sw);
  *(float4*)(gram + (((size_t)b) << 12) + q * 4) = s;
  if (fast){
    union { unsigned long long u; unsigned short h[4]; } u;
    u.h[0] = f2bf(sx); u.h[1] = f2bf(sy); u.h[2] = f2bf(sz); u.h[3] = f2bf(sw);
    *(unsigned long long*)(gbf + (((size_t)b) << 12) + q * 4) = u.u;
  }
}

// ---------------------------------------------------------------------------
// fused contextConv + structure-embedding + tokenConv. grid (128,48).
// LDS tiles use pitch-64 + XOR block swizzle (conflict-free b128 reads).
// ---------------------------------------------------------------------------
__global__ __launch_bounds__(256, 4) void fused_kernel(
    const float* __restrict__ x,
    const unsigned short* __restrict__ xbf,
    const float* __restrict__ ctx_b,
    const float* __restrict__ seW_w,
    const unsigned short* __restrict__ sWb,
    const float* __restrict__ seW_b,
    const float* __restrict__ gram,
    const unsigned short* __restrict__ gbf,
    const unsigned short* __restrict__ cwT,
    const unsigned short* __restrict__ twT,
    float* __restrict__ out,
    int fast)
{
  const int b = blockIdx.y;
  const int w0 = blockIdx.x * TWt;
  const int t = threadIdx.x;
  const int lane = t & 63;
  const int wave = t >> 6;
  const int lrow = lane & 15;
  const int lk = lane >> 4;

  // xs: 84x64 bf16 | sws: 80x64 bf16 | hsh: 66x64 bf16  -> 29440 B
  __shared__ __align__(16) unsigned char smem[(84 + 80 + 66) * 64 * 2];
  unsigned short* xs  = (unsigned short*)smem;
  unsigned short* sws = xs + 84 * 64;
  unsigned short* hsh = sws + 80 * 64;

  // ---- stage x columns w0-2 .. w0+81 as bf16 (zero-pad outside [0,W)),
  //      plus sWb rows (w0-1 .. w0+78, circular) in fast mode ----
  if (fast){
    for (int item = t; item < 84 * 8; item += 256){
      int i = item >> 3, seg = item & 7;
      int c = w0 - 2 + i;
      uint4 val = make_uint4(0u,0u,0u,0u);
      if (c >= 0 && c < Ww) val = *(const uint4*)(xbf + ((size_t)b*Ww + c)*Ff + seg*8);
      *(uint4*)(xs + swz(i, seg*8)) = val;
    }
    for (int item = t; item < 80 * 8; item += 256){
      int i = item >> 3, seg = item & 7;
      int hc = (w0 - 1 + i) & (Ww - 1);
      *(uint4*)(sws + swz(i, seg*8)) = *(const uint4*)(sWb + (size_t)hc*Ff + seg*8);
    }
  } else {
    for (int item = t; item < 84 * 8; item += 256){
      int i = item >> 3, seg = item & 7;
      int c = w0 - 2 + i;
      union { uint4 q; unsigned short s[8]; } u;
      if (c >= 0 && c < Ww){
        const float* xr = x + ((size_t)b*Ww + c)*Ff + seg*8;
        float4 a0 = *(const float4*)(xr);
        float4 a1 = *(const float4*)(xr + 4);
        u.s[0]=f2bf(a0.x); u.s[1]=f2bf(a0.y); u.s[2]=f2bf(a0.z); u.s[3]=f2bf(a0.w);
        u.s[4]=f2bf(a1.x); u.s[5]=f2bf(a1.y); u.s[6]=f2bf(a1.z); u.s[7]=f2bf(a1.w);
      } else {
        u.q = make_uint4(0u,0u,0u,0u);
      }
      *(uint4*)(xs + swz(i, seg*8)) = u.q;
    }
  }
  __syncthreads();

  // ---- phase A: xc GEMM (M=80,K=192,N=64) + xse GEMM (M=80,K=64,N=64) ----
  const int nt = wave;
  bf16x8 cw_frag[6];
  {
    const unsigned short* p = cwT + (nt*16 + lrow)*192 + lk*8;
#pragma unroll
    for (int kc = 0; kc < 6; ++kc) cw_frag[kc] = *(const bf16x8*)(p + kc*32);
  }
  bf16x8 se_frag[2];
  if (fast){
    const unsigned short* gp = gbf + (size_t)b*4096 + (nt*16 + lrow)*64;  // gram symmetric
#pragma unroll
    for (int kc = 0; kc < 2; ++kc) se_frag[kc] = *(const bf16x8*)(gp + kc*32 + lk*8);
  } else {
    const float* gb = gram + (size_t)b * 4096;
#pragma unroll
    for (int kc = 0; kc < 2; ++kc){
      union { bf16x8 v; unsigned short s[8]; } u;
#pragma unroll
      for (int j = 0; j < 8; ++j){
        int g = kc*32 + lk*8 + j;
        u.s[j] = f2bf(gb[g*64 + nt*16 + lrow]);
      }
      se_frag[kc] = u.v;
    }
  }

  f32x4 xc_acc[5] = {};
  f32x4 se_acc[5] = {};

#pragma unroll
  for (int mt = 0; mt < 5; ++mt){
#pragma unroll
    for (int kc = 0; kc < 6; ++kc){
      int kim = kc*32 + lk*8;
      int ktap = kim >> 6, fi = kim & 63;
      bf16x8 a = *(const bf16x8*)(xs + swz(mt*16 + lrow + ktap, fi));
      xc_acc[mt] = mfma16(a, cw_frag[kc], xc_acc[mt]);
    }
    if (fast){
#pragma unroll
      for (int kc = 0; kc < 2; ++kc){
        bf16x8 a = *(const bf16x8*)(sws + swz(mt*16 + lrow, kc*32 + lk*8));
        se_acc[mt] = mfma16(a, se_frag[kc], se_acc[mt]);
      }
    } else {
      int hc = (w0 - 1 + mt*16 + lrow) & (Ww - 1);
      const float* sp = seW_w + (size_t)hc * Ff;
#pragma unroll
      for (int kc = 0; kc < 2; ++kc){
        union { bf16x8 v; unsigned short s[8]; } u;
        float4 a0 = *(const float4*)(sp + kc*32 + lk*8);
        float4 a1 = *(const float4*)(sp + kc*32 + lk*8 + 4);
        u.s[0]=f2bf(a0.x); u.s[1]=f2bf(a0.y); u.s[2]=f2bf(a0.z); u.s[3]=f2bf(a0.w);
        u.s[4]=f2bf(a1.x); u.s[5]=f2bf(a1.y); u.s[6]=f2bf(a1.z); u.s[7]=f2bf(a1.w);
        se_acc[mt] = mfma16(u.v, se_frag[kc], se_acc[mt]);
      }
    }
  }

  // epilogue: h = xc + ctx_b + relu(xse + seW_b)
  {
    float cb = ctx_b[nt*16 + lrow];
#pragma unroll
    for (int mt = 0; mt < 5; ++mt){
#pragma unroll
      for (int r = 0; r < 4; ++r){
        int j = mt*16 + lk*4 + r;
        if (j < 66){
          int hc = (w0 - 1 + j) & (Ww - 1);
          float se = se_acc[mt][r] + seW_b[hc];
          se = se > 0.f ? se : 0.f;
          hsh[swz(j, nt*16 + lrow)] = f2bf(xc_acc[mt][r] + cb + se);
        }
      }
    }
  }
  __syncthreads();

  // ---- patch circular-wrap slots (only tiles 0 and 127) ----
  if (blockIdx.x == 0 || blockIdx.x == (Ww/TWt - 1)){
    const int j  = (blockIdx.x == 0) ? 0 : 65;
    const int hc = (blockIdx.x == 0) ? (Ww - 1) : 0;
    if (t < 64){
      const int f = t;
      float a = ctx_b[f];
      for (int ktap = 0; ktap < 3; ++ktap){
        int c = hc + ktap - 1;
        if (c >= 0 && c < Ww){
          const float* xr = x + ((size_t)b*Ww + c)*Ff;
          const unsigned short* wr = cwT + f*192 + ktap*64;
          for (int fi = 0; fi < 64; ++fi) a += xr[fi] * bf2f(wr[fi]);
        }
      }
      const float* gb = gram + (size_t)b * 4096;
      const float* sp = seW_w + (size_t)hc * Ff;
      float se = seW_b[hc];
      for (int g = 0; g < 64; ++g) se += sp[g] * gb[g*64 + f];
      se = se > 0.f ? se : 0.f;
      hsh[swz(j, f)] = f2bf(a + se);
    }
    __syncthreads();
  }

  // ---- phase C: tokenConv GEMM (M=64, K=192, N=128) ----
  bf16x8 tw_frag[2][6];
#pragma unroll
  for (int q = 0; q < 2; ++q){
    const unsigned short* p = twT + ((wave*2 + q)*16 + lrow)*192 + lk*8;
#pragma unroll
    for (int kc = 0; kc < 6; ++kc) tw_frag[q][kc] = *(const bf16x8*)(p + kc*32);
  }
  f32x4 oacc[4][2] = {};
#pragma unroll
  for (int mt = 0; mt < 4; ++mt){
#pragma unroll
    for (int kc = 0; kc < 6; ++kc){
      int kim = kc*32 + lk*8;
      int ktap = kim >> 6, fi = kim & 63;
      bf16x8 a = *(const bf16x8*)(hsh + swz(mt*16 + lrow + ktap, fi));
#pragma unroll
      for (int q = 0; q < 2; ++q)
        oacc[mt][q] = mfma16(a, tw_frag[q][kc], oacc[mt][q]);
    }
  }

  // ---- epilogue: direct coalesced stores (64 B segments per 16 lanes) ----
#pragma unroll
  for (int mt = 0; mt < 4; ++mt){
#pragma unroll
    for (int q = 0; q < 2; ++q)
#pragma unroll
      for (int r = 0; r < 4; ++r){
        int row = w0 + mt*16 + lk*4 + r;
        int d   = (wave*2 + q)*16 + lrow;
        out[((size_t)b*Ww + row)*Dd + d] = oacc[mt][q][r];
      }
  }
}

// ---------------------------------------------------------------------------
extern "C" void kernel_launch(void* const* d_in, const int* in_sizes, int n_in,
                              void* d_out, int out_size, void* d_ws, size_t ws_size,
                              hipStream_t stream)
{
  const float* x       = (const float*)d_in[0];
  const float* ctx_w   = (const float*)d_in[1];
  const float* ctx_b   = (const float*)d_in[2];
  const float* token_w = (const float*)d_in[3];
  const float* seW_w   = (const float*)d_in[4];
  const float* seW_b   = (const float*)d_in[5];
  float* out = (float*)d_out;

  char* ws = (char*)d_ws;
  float*          gramP = (float*)(ws + WS_GRAMP);
  float*          gram  = (float*)(ws + WS_GRAM);
  unsigned short* twT   = (unsigned short*)(ws + WS_TWT);
  unsigned short* cwT   = (unsigned short*)(ws + WS_CWT);
  unsigned short* gbf   = (unsigned short*)(ws + WS_GBF);
  unsigned short* sWb   = (unsigned short*)(ws + WS_SWB);
  float*          rinvb = (float*)(ws + WS_RINV);
  unsigned short* xbf   = (unsigned short*)(ws + WS_XBF);

  const int fast = (ws_size >= (size_t)WS_TOTAL) ? 1 : 0;

  prep_weights<<<dim3(400), dim3(256), 0, stream>>>(ctx_w, token_w, seW_w, cwT, twT, sWb, fast);
  if (fast) xprep<<<dim3(6144), dim3(256), 0, stream>>>(x, xbf, rinvb);
  gram_kernel<<<dim3(NSLAB, Bb), dim3(256), 0, stream>>>(x, xbf, rinvb, gramP, fast);
  gram_reduce<<<dim3(192), dim3(256), 0, stream>>>(gramP, gram, gbf, fast);
  fused_kernel<<<dim3(Ww/TWt, Bb), dim3(256), 0, stream>>>(
      x, xbf, ctx_b, seW_w, sWb, seW_b, gram, gbf, cwT, twT, out, fast);
}

// Round 5
// 362.854 us; speedup vs baseline: 1.0529x; 1.0132x over previous
//
#include <hip/hip_runtime.h>
#include <stdint.h>

#define Bb 48
#define Ww 8192
#define Ff 64
#define Dd 128
#define TWt 64
#define NSLAB 32

// ws layout (bytes)
#define WS_GRAMP 0u                                   // 32*48*4096*4 = 25165824
#define WS_GRAM  25165824u                            // 48*4096*4    = 786432
#define WS_TWT   25952256u                            // 128*192*2    = 49152
#define WS_CWT   26001408u                            // 64*192*2     = 24576
#define WS_GBF   26025984u                            // 48*4096*2    = 393216
#define WS_SWB   26419200u                            // 8192*64*2    = 1048576
#define WS_XBF   27467776u                            // 48*8192*64*2 = 50331648
#define WS_TOTAL (27467776ull + 50331648ull)          // 77799424

typedef __bf16 bf16x8 __attribute__((ext_vector_type(8)));
typedef float f32x4 __attribute__((ext_vector_type(4)));

__device__ __forceinline__ float bf2f(unsigned short u){
  union { unsigned int i; float f; } v; v.i = ((unsigned int)u) << 16; return v.f;
}
__device__ __forceinline__ unsigned short f2bf(float f){
  union { float f; unsigned int i; } v; v.f = f;
  unsigned int i = v.i;
  return (unsigned short)((i + 0x7fffu + ((i >> 16) & 1u)) >> 16);
}
__device__ __forceinline__ f32x4 mfma16(bf16x8 a, bf16x8 b, f32x4 c){
  return __builtin_amdgcn_mfma_f32_16x16x32_bf16(a, b, c, 0, 0, 0);
}

// XOR block-swizzled LDS offset: 64-short rows, 8-short (16B) blocks,
// block index XORed with (row&7). Conflict-free stride-row ds_read_b128.
__device__ __forceinline__ int swz(int row, int col){
  return row * 64 + ((((col >> 3) ^ (row & 7))) << 3) + (col & 7);
}

// ---------------------------------------------------------------------------
// merged weight prep: blocks 0..143 pack cwT/twT, blocks 144..399 convert seW_w
// ---------------------------------------------------------------------------
__global__ __launch_bounds__(256) void prep_weights(const float* __restrict__ ctx_w,
                                                    const float* __restrict__ token_w,
                                                    const float* __restrict__ seW_w,
                                                    unsigned short* __restrict__ cwT,
                                                    unsigned short* __restrict__ twT,
                                                    unsigned short* __restrict__ sWb,
                                                    int fast)
{
  const int bx = blockIdx.x;
  if (bx < 144){
    int idx = bx * 256 + threadIdx.x;
    const int ntw = Dd * 192;
    if (idx < ntw){
      int d = idx / 192, kim = idx % 192;
      int ktap = kim >> 6, fi = kim & 63;
      twT[idx] = f2bf(token_w[(d * Ff + fi) * 3 + ktap]);
    } else if (idx < ntw + Ff * 192){
      int i2 = idx - ntw;
      int f = i2 / 192, kim = i2 % 192;
      int ktap = kim >> 6, fi = kim & 63;
      cwT[i2] = f2bf(ctx_w[(f * Ff + fi) * 3 + ktap]);
    }
  } else if (fast){
    int i = ((bx - 144) * 256 + threadIdx.x) * 8;   // 524288 elems, 256 blocks
    float4 a0 = *(const float4*)(seW_w + i);
    float4 a1 = *(const float4*)(seW_w + i + 4);
    union { uint4 q; unsigned short s[8]; } u;
    u.s[0]=f2bf(a0.x); u.s[1]=f2bf(a0.y); u.s[2]=f2bf(a0.z); u.s[3]=f2bf(a0.w);
    u.s[4]=f2bf(a1.x); u.s[5]=f2bf(a1.y); u.s[6]=f2bf(a1.z); u.s[7]=f2bf(a1.w);
    *(uint4*)(sWb + i) = u.q;
  }
}

// ---------------------------------------------------------------------------
// gramP[slab][b] = partial srcn^T srcn over a 256-row K-chunk, reading x fp32
// directly; emits xbf (bf16 copy of x) inline; next-subtile loads prefetched
// into registers before the barrier so HBM latency hides under MFMA.
// Swizzled LDS tile. grid (NSLAB, 48).
// ---------------------------------------------------------------------------
__global__ __launch_bounds__(256) void gram_kernel(const float* __restrict__ x,
                                                   unsigned short* __restrict__ xbf,
                                                   float* __restrict__ gramP,
                                                   int writeXbf)
{
  const int b = blockIdx.y;
  const int w_base = blockIdx.x * (Ww / NSLAB);   // 256 rows per slab
  const int t = threadIdx.x;
  const int lane = t & 63;
  const int wave = t >> 6;
  const int lrow = lane & 15;
  const int lk = lane >> 4;

  __shared__ unsigned short st[64 * 64];

  f32x4 acc[4] = {};

  const int wl = t >> 2;           // row within 64-row sub-tile
  const int f0 = (t & 3) * 16;     // 16 features per thread

  float v[16];
  {
    const float* xr = x + ((size_t)b * Ww + (size_t)(w_base + wl)) * Ff + f0;
    *(float4*)(v)      = *(const float4*)(xr);
    *(float4*)(v + 4)  = *(const float4*)(xr + 4);
    *(float4*)(v + 8)  = *(const float4*)(xr + 8);
    *(float4*)(v + 12) = *(const float4*)(xr + 12);
  }

  for (int sc = 0; sc < 4; ++sc) {
    const size_t rowg = (size_t)b * Ww + (size_t)(w_base + sc * 64 + wl);

    float ss = 0.f;
#pragma unroll
    for (int i = 0; i < 16; ++i) ss += v[i] * v[i];
    ss += __shfl_xor(ss, 1);
    ss += __shfl_xor(ss, 2);
    float rinv = rsqrtf(ss);

    union { uint4 q[2]; unsigned short s[16]; } u;
#pragma unroll
    for (int i = 0; i < 16; ++i){
      u.s[i] = f2bf(v[i]);
      st[swz(f0 + i, wl)] = f2bf(v[i] * rinv);
    }
    if (writeXbf){
      unsigned short* dst = xbf + rowg * Ff + f0;
      *(uint4*)(dst)     = u.q[0];
      *(uint4*)(dst + 8) = u.q[1];
    }

    // prefetch next sub-tile before the barrier (hides under MFMA section)
    float vn[16];
    if (sc < 3){
      const float* xr = x + ((size_t)b * Ww + (size_t)(w_base + (sc+1) * 64 + wl)) * Ff + f0;
      *(float4*)(vn)      = *(const float4*)(xr);
      *(float4*)(vn + 4)  = *(const float4*)(xr + 4);
      *(float4*)(vn + 8)  = *(const float4*)(xr + 8);
      *(float4*)(vn + 12) = *(const float4*)(xr + 12);
    }

    __syncthreads();
#pragma unroll
    for (int kc = 0; kc < 2; ++kc){
      const int kw = kc * 32 + lk * 8;
      bf16x8 bfr = *(const bf16x8*)(st + swz(wave * 16 + lrow, kw));
#pragma unroll
      for (int mt = 0; mt < 4; ++mt){
        bf16x8 af = *(const bf16x8*)(st + swz(mt * 16 + lrow, kw));
        acc[mt] = mfma16(af, bfr, acc[mt]);
      }
    }
    __syncthreads();

    if (sc < 3){
#pragma unroll
      for (int i = 0; i < 16; ++i) v[i] = vn[i];
    }
  }

  float* gb = gramP + ((size_t)(blockIdx.x * Bb + b)) * 4096;
#pragma unroll
  for (int mt = 0; mt < 4; ++mt)
#pragma unroll
    for (int r = 0; r < 4; ++r){
      int f = mt * 16 + lk * 4 + r;   // D row
      int g = wave * 16 + lrow;       // D col
      gb[f * 64 + g] = acc[mt][r];
    }
}

// ---------------------------------------------------------------------------
// reduce the NSLAB partial grams -> gram (fp32) and gbf (bf16). grid (192).
// ---------------------------------------------------------------------------
__global__ __launch_bounds__(256) void gram_reduce(const float* __restrict__ gramP,
                                                   float* __restrict__ gram,
                                                   unsigned short* __restrict__ gbf,
                                                   int fast)
{
  int i = blockIdx.x * 256 + threadIdx.x;   // 49152 threads, one float4 each
  int b = i >> 10;                          // 1024 float4 per batch
  int q = i & 1023;
  float sx = 0.f, sy = 0.f, sz = 0.f, sw = 0.f;
#pragma unroll
  for (int sl = 0; sl < NSLAB; ++sl){
    const float4 v = *(const float4*)(gramP + (((size_t)(sl * Bb + b)) << 12) + q * 4);
    sx += v.x; sy += v.y; sz += v.z; sw += v.w;
  }
  float4 s = make_float4(sx, sy, sz, sw);
  *(float4*)(gram + (((size_t)b) << 12) + q * 4) = s;
  if (fast){
    union { unsigned long long u; unsigned short h[4]; } u;
    u.h[0] = f2bf(sx); u.h[1] = f2bf(sy); u.h[2] = f2bf(sz); u.h[3] = f2bf(sw);
    *(unsigned long long*)(gbf + (((size_t)b) << 12) + q * 4) = u.u;
  }
}

// ---------------------------------------------------------------------------
// fused contextConv + structure-embedding + tokenConv. grid (128,48).
// LDS tiles use pitch-64 + XOR block swizzle (conflict-free b128 reads).
// ---------------------------------------------------------------------------
__global__ __launch_bounds__(256, 4) void fused_kernel(
    const float* __restrict__ x,
    const unsigned short* __restrict__ xbf,
    const float* __restrict__ ctx_b,
    const float* __restrict__ seW_w,
    const unsigned short* __restrict__ sWb,
    const float* __restrict__ seW_b,
    const float* __restrict__ gram,
    const unsigned short* __restrict__ gbf,
    const unsigned short* __restrict__ cwT,
    const unsigned short* __restrict__ twT,
    float* __restrict__ out,
    int fast)
{
  const int b = blockIdx.y;
  const int w0 = blockIdx.x * TWt;
  const int t = threadIdx.x;
  const int lane = t & 63;
  const int wave = t >> 6;
  const int lrow = lane & 15;
  const int lk = lane >> 4;

  // xs: 84x64 bf16 | sws: 80x64 bf16 | hsh: 66x64 bf16  -> 29440 B
  __shared__ __align__(16) unsigned char smem[(84 + 80 + 66) * 64 * 2];
  unsigned short* xs  = (unsigned short*)smem;
  unsigned short* sws = xs + 84 * 64;
  unsigned short* hsh = sws + 80 * 64;

  // ---- stage x columns w0-2 .. w0+81 as bf16 (zero-pad outside [0,W)),
  //      plus sWb rows (w0-1 .. w0+78, circular) in fast mode ----
  if (fast){
    for (int item = t; item < 84 * 8; item += 256){
      int i = item >> 3, seg = item & 7;
      int c = w0 - 2 + i;
      uint4 val = make_uint4(0u,0u,0u,0u);
      if (c >= 0 && c < Ww) val = *(const uint4*)(xbf + ((size_t)b*Ww + c)*Ff + seg*8);
      *(uint4*)(xs + swz(i, seg*8)) = val;
    }
    for (int item = t; item < 80 * 8; item += 256){
      int i = item >> 3, seg = item & 7;
      int hc = (w0 - 1 + i) & (Ww - 1);
      *(uint4*)(sws + swz(i, seg*8)) = *(const uint4*)(sWb + (size_t)hc*Ff + seg*8);
    }
  } else {
    for (int item = t; item < 84 * 8; item += 256){
      int i = item >> 3, seg = item & 7;
      int c = w0 - 2 + i;
      union { uint4 q; unsigned short s[8]; } u;
      if (c >= 0 && c < Ww){
        const float* xr = x + ((size_t)b*Ww + c)*Ff + seg*8;
        float4 a0 = *(const float4*)(xr);
        float4 a1 = *(const float4*)(xr + 4);
        u.s[0]=f2bf(a0.x); u.s[1]=f2bf(a0.y); u.s[2]=f2bf(a0.z); u.s[3]=f2bf(a0.w);
        u.s[4]=f2bf(a1.x); u.s[5]=f2bf(a1.y); u.s[6]=f2bf(a1.z); u.s[7]=f2bf(a1.w);
      } else {
        u.q = make_uint4(0u,0u,0u,0u);
      }
      *(uint4*)(xs + swz(i, seg*8)) = u.q;
    }
  }
  __syncthreads();

  // ---- phase A: xc GEMM (M=80,K=192,N=64) + xse GEMM (M=80,K=64,N=64) ----
  const int nt = wave;
  bf16x8 cw_frag[6];
  {
    const unsigned short* p = cwT + (nt*16 + lrow)*192 + lk*8;
#pragma unroll
    for (int kc = 0; kc < 6; ++kc) cw_frag[kc] = *(const bf16x8*)(p + kc*32);
  }
  bf16x8 se_frag[2];
  if (fast){
    const unsigned short* gp = gbf + (size_t)b*4096 + (nt*16 + lrow)*64;  // gram symmetric
#pragma unroll
    for (int kc = 0; kc < 2; ++kc) se_frag[kc] = *(const bf16x8*)(gp + kc*32 + lk*8);
  } else {
    const float* gb = gram + (size_t)b * 4096;
#pragma unroll
    for (int kc = 0; kc < 2; ++kc){
      union { bf16x8 v; unsigned short s[8]; } u;
#pragma unroll
      for (int j = 0; j < 8; ++j){
        int g = kc*32 + lk*8 + j;
        u.s[j] = f2bf(gb[g*64 + nt*16 + lrow]);
      }
      se_frag[kc] = u.v;
    }
  }

  f32x4 xc_acc[5] = {};
  f32x4 se_acc[5] = {};

#pragma unroll
  for (int mt = 0; mt < 5; ++mt){
#pragma unroll
    for (int kc = 0; kc < 6; ++kc){
      int kim = kc*32 + lk*8;
      int ktap = kim >> 6, fi = kim & 63;
      bf16x8 a = *(const bf16x8*)(xs + swz(mt*16 + lrow + ktap, fi));
      xc_acc[mt] = mfma16(a, cw_frag[kc], xc_acc[mt]);
    }
    if (fast){
#pragma unroll
      for (int kc = 0; kc < 2; ++kc){
        bf16x8 a = *(const bf16x8*)(sws + swz(mt*16 + lrow, kc*32 + lk*8));
        se_acc[mt] = mfma16(a, se_frag[kc], se_acc[mt]);
      }
    } else {
      int hc = (w0 - 1 + mt*16 + lrow) & (Ww - 1);
      const float* sp = seW_w + (size_t)hc * Ff;
#pragma unroll
      for (int kc = 0; kc < 2; ++kc){
        union { bf16x8 v; unsigned short s[8]; } u;
        float4 a0 = *(const float4*)(sp + kc*32 + lk*8);
        float4 a1 = *(const float4*)(sp + kc*32 + lk*8 + 4);
        u.s[0]=f2bf(a0.x); u.s[1]=f2bf(a0.y); u.s[2]=f2bf(a0.z); u.s[3]=f2bf(a0.w);
        u.s[4]=f2bf(a1.x); u.s[5]=f2bf(a1.y); u.s[6]=f2bf(a1.z); u.s[7]=f2bf(a1.w);
        se_acc[mt] = mfma16(u.v, se_frag[kc], se_acc[mt]);
      }
    }
  }

  // epilogue: h = xc + ctx_b + relu(xse + seW_b)
  {
    float cb = ctx_b[nt*16 + lrow];
#pragma unroll
    for (int mt = 0; mt < 5; ++mt){
#pragma unroll
      for (int r = 0; r < 4; ++r){
        int j = mt*16 + lk*4 + r;
        if (j < 66){
          int hc = (w0 - 1 + j) & (Ww - 1);
          float se = se_acc[mt][r] + seW_b[hc];
          se = se > 0.f ? se : 0.f;
          hsh[swz(j, nt*16 + lrow)] = f2bf(xc_acc[mt][r] + cb + se);
        }
      }
    }
  }
  __syncthreads();

  // ---- patch circular-wrap slots (only tiles 0 and 127) ----
  if (blockIdx.x == 0 || blockIdx.x == (Ww/TWt - 1)){
    const int j  = (blockIdx.x == 0) ? 0 : 65;
    const int hc = (blockIdx.x == 0) ? (Ww - 1) : 0;
    if (t < 64){
      const int f = t;
      float a = ctx_b[f];
      for (int ktap = 0; ktap < 3; ++ktap){
        int c = hc + ktap - 1;
        if (c >= 0 && c < Ww){
          const float* xr = x + ((size_t)b*Ww + c)*Ff;
          const unsigned short* wr = cwT + f*192 + ktap*64;
          for (int fi = 0; fi < 64; ++fi) a += xr[fi] * bf2f(wr[fi]);
        }
      }
      const float* gb = gram + (size_t)b * 4096;
      const float* sp = seW_w + (size_t)hc * Ff;
      float se = seW_b[hc];
      for (int g = 0; g < 64; ++g) se += sp[g] * gb[g*64 + f];
      se = se > 0.f ? se : 0.f;
      hsh[swz(j, f)] = f2bf(a + se);
    }
    __syncthreads();
  }

  // ---- phase C: tokenConv GEMM (M=64, K=192, N=128) ----
  bf16x8 tw_frag[2][6];
#pragma unroll
  for (int q = 0; q < 2; ++q){
    const unsigned short* p = twT + ((wave*2 + q)*16 + lrow)*192 + lk*8;
#pragma unroll
    for (int kc = 0; kc < 6; ++kc) tw_frag[q][kc] = *(const bf16x8*)(p + kc*32);
  }
  f32x4 oacc[4][2] = {};
#pragma unroll
  for (int mt = 0; mt < 4; ++mt){
#pragma unroll
    for (int kc = 0; kc < 6; ++kc){
      int kim = kc*32 + lk*8;
      int ktap = kim >> 6, fi = kim & 63;
      bf16x8 a = *(const bf16x8*)(hsh + swz(mt*16 + lrow + ktap, fi));
#pragma unroll
      for (int q = 0; q < 2; ++q)
        oacc[mt][q] = mfma16(a, tw_frag[q][kc], oacc[mt][q]);
    }
  }

  // ---- epilogue: direct coalesced stores (64 B segments per 16 lanes) ----
#pragma unroll
  for (int mt = 0; mt < 4; ++mt){
#pragma unroll
    for (int q = 0; q < 2; ++q)
#pragma unroll
      for (int r = 0; r < 4; ++r){
        int row = w0 + mt*16 + lk*4 + r;
        int d   = (wave*2 + q)*16 + lrow;
        out[((size_t)b*Ww + row)*Dd + d] = oacc[mt][q][r];
      }
  }
}

// ---------------------------------------------------------------------------
extern "C" void kernel_launch(void* const* d_in, const int* in_sizes, int n_in,
                              void* d_out, int out_size, void* d_ws, size_t ws_size,
                              hipStream_t stream)
{
  const float* x       = (const float*)d_in[0];
  const float* ctx_w   = (const float*)d_in[1];
  const float* ctx_b   = (const float*)d_in[2];
  const float* token_w = (const float*)d_in[3];
  const float* seW_w   = (const float*)d_in[4];
  const float* seW_b   = (const float*)d_in[5];
  float* out = (float*)d_out;

  char* ws = (char*)d_ws;
  float*          gramP = (float*)(ws + WS_GRAMP);
  float*          gram  = (float*)(ws + WS_GRAM);
  unsigned short* twT   = (unsigned short*)(ws + WS_TWT);
  unsigned short* cwT   = (unsigned short*)(ws + WS_CWT);
  unsigned short* gbf   = (unsigned short*)(ws + WS_GBF);
  unsigned short* sWb   = (unsigned short*)(ws + WS_SWB);
  unsigned short* xbf   = (unsigned short*)(ws + WS_XBF);

  const int fast = (ws_size >= (size_t)WS_TOTAL) ? 1 : 0;

  prep_weights<<<dim3(400), dim3(256), 0, stream>>>(ctx_w, token_w, seW_w, cwT, twT, sWb, fast);
  gram_kernel<<<dim3(NSLAB, Bb), dim3(256), 0, stream>>>(x, xbf, gramP, fast);
  gram_reduce<<<dim3(192), dim3(256), 0, stream>>>(gramP, gram, gbf, fast);
  fused_kernel<<<dim3(Ww/TWt, Bb), dim3(256), 0, stream>>>(
      x, xbf, ctx_b, seW_w, sWb, seW_b, gram, gbf, cwT, twT, out, fast);
}